// Round 3
// baseline (656.879 us; speedup 1.0000x reference)
//
#include <hip/hip_runtime.h>

// CrissCrossAttention on MI355X (gfx950), fp16-MFMA pipeline, fp32 accumulate.
//
// Pipeline (4 launches, all on `stream`):
//   0) prep_w    : qkv_w, out_w fp32 -> f16 (once, 260 KB)
//   1) qkv_gemm  : qkv[b,192,p] = f16(qkv_w @ x + qkv_b), written in BOTH
//                  natural [c][h][w] and transposed [c][w][h] layouts
//                  (2D 8h x 16w p-tiles, C bounced through LDS)  -> no t1
//   2) cc_attn   : z=0 horizontal (qkvT -> ahT), z=1 vertical (qkv -> avN)
//   3) out_proj  : out = gamma*(out_w @ (ahT^T + avN)) + out_b + x
//                  (2D p-tiles; reads ahT directly -> no t2)
//
// R3 changes vs R2 (601 us): killed both transpose kernels via dual-layout
// epilogue (qkv_gemm) and transposed-input staging (out_proj); f16 weight
// pre-conversion; X/W global->reg prefetch in qkv_gemm K-loop.
//
// Workspace: qkv 48 | qkvT 48 | ahT 16 | avN 16 MB | wq16 192K | wo16 64K

typedef _Float16 f16;
typedef _Float16 f16x4 __attribute__((ext_vector_type(4)));
typedef _Float16 f16x8 __attribute__((ext_vector_type(8)));
typedef float f32x4 __attribute__((ext_vector_type(4)));

#define MFMA16(a, b, c) __builtin_amdgcn_mfma_f32_16x16x32_f16(a, b, c, 0, 0, 0)

constexpr int CIN = 512;
constexpr int COUT = 64;       // per q/k/v
constexpr int HW = 128;
constexpr int P = HW * HW;     // 16384 pixels per batch
constexpr int QKV_CH = 192;

// ---------------------------------------------------------------------------
// Kernel 0: one-shot weight conversion fp32 -> f16.
// qkv_w 192x512 (24576 float4) + out_w 512x64 (8192 float4) = 32768 float4.
// ---------------------------------------------------------------------------
__global__ __launch_bounds__(256) void prep_w(
    const float* __restrict__ qw, const float* __restrict__ ow,
    f16* __restrict__ qw16, f16* __restrict__ ow16)
{
  int i = blockIdx.x * 256 + threadIdx.x;    // 0..32767
  const float* src;
  f16* dst;
  int off;
  if (i < 24576) { src = qw; dst = qw16; off = i; }
  else           { src = ow; dst = ow16; off = i - 24576; }
  const float4 v = *(const float4*)(src + (size_t)off * 4);
  f16x4 o;
  o[0] = (f16)v.x; o[1] = (f16)v.y; o[2] = (f16)v.z; o[3] = (f16)v.w;
  *(f16x4*)(dst + (size_t)off * 4) = o;
}

// ---------------------------------------------------------------------------
// Kernel 1: QKV projection GEMM, dual-layout output.
// grid (128 tiles, 8 b), block 256 (4 waves, 2x2 wave grid).
// Tile = 8h x 16w (p_local = hh*16+ww), so x staging reads full 64B lines and
// both output layouts get >=16B contiguous stores via an LDS C-tile bounce.
// MFMA: A = X frag (p rows), B = W frag (m rows); D row->p, col->m.
// ---------------------------------------------------------------------------
__global__ __launch_bounds__(256) void qkv_gemm(
    const float* __restrict__ x, const f16* __restrict__ w16,
    const float* __restrict__ bias, f16* __restrict__ qkv,
    f16* __restrict__ qkvT)
{
  // Wl: [192 m][32 k] stride 40; Xt: [128 p][32 k] stride 40, XOR-swizzled.
  // Cl (epilogue, 64m x 128p stride 136, col-group XOR by m&7) aliases pool.
  __shared__ __attribute__((aligned(16))) f16 pool[QKV_CH * 40 + 128 * 40];
  f16* Wl = pool;
  f16* Xt = pool + QKV_CH * 40;
  f16* Cl = pool;
  const int bx = blockIdx.x;
  const int h0 = (bx >> 3) * 8, w0 = (bx & 7) * 16;
  const int b = blockIdx.y;
  const float* xb = x + (size_t)b * CIN * P;
  const int t = threadIdx.x;
  const int lane = t & 63, wv = t >> 6;
  const int quad = lane >> 4, l15 = lane & 15;
  const int wm = (wv >> 1) * 32, wn = (wv & 1) * 64;

  // staging-assignment constants (per thread)
  // W: 3 chunks of f16x8: c=t+it*256, row=c>>2, c8=(c&3)*8
  // X: 4 chunks of float4: c=t+it*256, kr=c>>5, hh=(c&31)>>2, w4=(c&3)*4
  f16x8 wvr[3];
  float4 xvr[4];
#define LOADW(s)                                                          \
  _Pragma("unroll") for (int it = 0; it < 3; ++it) {                      \
    int c = t + it * 256;                                                 \
    wvr[it] = *(const f16x8*)(w16 + (size_t)(c >> 2) * CIN + (s) * 32 +   \
                              (c & 3) * 8);                               \
  }
#define LOADX(s)                                                          \
  _Pragma("unroll") for (int it = 0; it < 4; ++it) {                      \
    int c = t + it * 256;                                                 \
    int kr = c >> 5, sub = c & 31;                                        \
    xvr[it] = *(const float4*)(xb + (size_t)((s) * 32 + kr) * P +         \
                               (h0 + (sub >> 2)) * 128 + w0 + (sub & 3) * 4); \
  }

  LOADW(0);
  LOADX(0);
  f32x4 acc[3][4][2] = {};   // [m-tile][p-sub][m-sub]
  for (int s = 0; s < 16; ++s) {
    // write staged regs to LDS
#pragma unroll
    for (int it = 0; it < 3; ++it) {
      int c = t + it * 256;
      *(f16x8*)&Wl[(c >> 2) * 40 + (c & 3) * 8] = wvr[it];
    }
#pragma unroll
    for (int it = 0; it < 4; ++it) {
      int c = t + it * 256;
      int kr = c >> 5, sub = c & 31;
      int pb = (sub >> 2) * 16 + (sub & 3) * 4;
      float vv[4] = {xvr[it].x, xvr[it].y, xvr[it].z, xvr[it].w};
#pragma unroll
      for (int j = 0; j < 4; ++j) {
        int p = pb + j;
        int kc = kr ^ (((p >> 3) & 3) << 3);
        Xt[p * 40 + kc] = (f16)vv[j];
      }
    }
    __syncthreads();
    if (s < 15) { LOADW(s + 1); LOADX(s + 1); }   // overlap with MFMA below
    f16x8 xf[4];
#pragma unroll
    for (int ps = 0; ps < 4; ++ps) {
      int pr = wn + ps * 16 + l15;
      int kb = (quad * 8) ^ (((pr >> 3) & 3) << 3);
      xf[ps] = *(const f16x8*)&Xt[pr * 40 + kb];
    }
#pragma unroll
    for (int mt = 0; mt < 3; ++mt) {
      f16x8 wf[2];
#pragma unroll
      for (int ms = 0; ms < 2; ++ms)
        wf[ms] = *(const f16x8*)&Wl[(mt * 64 + wm + ms * 16 + l15) * 40 + quad * 8];
#pragma unroll
      for (int ps = 0; ps < 4; ++ps)
#pragma unroll
        for (int ms = 0; ms < 2; ++ms)
          acc[mt][ps][ms] = MFMA16(xf[ps], wf[ms], acc[mt][ps][ms]);
    }
    __syncthreads();
  }
#undef LOADW
#undef LOADX

  // Epilogue: per m-tile, scatter acc(+bias) into Cl, then cooperative
  // readout in both layouts with f16x8 stores.
  f16* obN = qkv + (size_t)b * QKV_CH * P;
  f16* obT = qkvT + (size_t)b * QKV_CH * P;
#pragma unroll
  for (int mt = 0; mt < 3; ++mt) {
#pragma unroll
    for (int ms = 0; ms < 2; ++ms) {
      int ml = wm + ms * 16 + l15;
      float bi = bias[mt * 64 + ml];
#pragma unroll
      for (int ps = 0; ps < 4; ++ps) {
        int pst = wn + ps * 16 + quad * 4;
        int col = (((pst >> 3) ^ (ml & 7)) << 3) + (pst & 7);
        f16x4 tv;
#pragma unroll
        for (int r = 0; r < 4; ++r) tv[r] = (f16)(acc[mt][ps][ms][r] + bi);
        *(f16x4*)&Cl[ml * 136 + col] = tv;
      }
    }
    __syncthreads();
    // natural: [m][h0+hh][w0 + w8..w8+7]
#pragma unroll
    for (int it = 0; it < 4; ++it) {
      int c = t + it * 256;
      int ml = c >> 4, sub = c & 15;
      int hh = sub >> 1, w8 = (sub & 1) * 8;
      int pst = hh * 16 + w8;
      int col = (((pst >> 3) ^ (ml & 7)) << 3);
      f16x8 rd = *(const f16x8*)&Cl[ml * 136 + col];
      *(f16x8*)(obN + (size_t)(mt * 64 + ml) * P + (h0 + hh) * 128 + w0 + w8) = rd;
    }
    // transposed: [m][w0+ww][h0 .. h0+7]
#pragma unroll
    for (int it = 0; it < 4; ++it) {
      int c = t + it * 256;
      int ml = c >> 4, ww = c & 15;
      f16 tmp[8];
#pragma unroll
      for (int hh = 0; hh < 8; ++hh) {
        int p = hh * 16 + ww;
        int col = (((p >> 3) ^ (ml & 7)) << 3) + (p & 7);
        tmp[hh] = Cl[ml * 136 + col];
      }
      *(f16x8*)(obT + (size_t)(mt * 64 + ml) * P + (size_t)(w0 + ww) * 128 + h0) =
          *(const f16x8*)tmp;
    }
    __syncthreads();
  }
}

// ---------------------------------------------------------------------------
// Kernel 2: criss-cross attention over one line (row or column).
// grid (128 s, 8 b, 2 branch), block 256 (4 waves, each owns a 16-q strip).
// Input slice layout (both branches): elem(o, j) = src[b*192*P + o*P + s*128 + j]
// E[64q x 64k] = sum_j Q[q,j] K[k,j]  -> softmax over k -> O = P V [64q x 128j]
// LDS: Kl 64x136 (K; reused as Al stride 72 after E, then Ol stride 136 after
// PV), Vt 128x72 swizzled.  Total 35.8 KB -> 4 blocks/CU.
// ---------------------------------------------------------------------------
__global__ __launch_bounds__(256, 4) void cc_attn(
    const f16* __restrict__ qkvT, const f16* __restrict__ qkvN,
    f16* __restrict__ outT, f16* __restrict__ outN)
{
  __shared__ __attribute__((aligned(16))) f16 smem[64 * 136 + 128 * 72];
  f16* Kl = smem;
  f16* Vt = smem + 64 * 136;
  f16* Al = smem;  // reuse of Kl region after E (wave-private rows)
  f16* Ol = smem;  // reuse of Kl region after PV (wave-private rows)
  const int s = blockIdx.x, b = blockIdx.y;
  const f16* src = blockIdx.z ? qkvN : qkvT;
  f16* dst = blockIdx.z ? outN : outT;
  const f16* base = src + (size_t)b * QKV_CH * P + (size_t)s * HW;
  const int t = threadIdx.x;
  const int lane = t & 63, wv = t >> 6;
  const int quad = lane >> 4, l15 = lane & 15;
  const int m0 = wv * 16;  // this wave's q-strip

  // Q fragments straight from global into regs (wave-private rows m0..m0+15).
  f16x8 aq[4];
#pragma unroll
  for (int kk = 0; kk < 4; ++kk)
    aq[kk] = *(const f16x8*)(base + (size_t)(m0 + l15) * P + kk * 32 + quad * 8);

  // stage K (natural) and V (transposed+swizzled): 1024 chunks of 8 each
  for (int it = 0; it < 4; ++it) {
    int c = t + it * 256;
    int row = c >> 4, c8 = (c & 15) * 8;
    *(f16x8*)&Kl[row * 136 + c8] =
        *(const f16x8*)(base + (size_t)(64 + row) * P + c8);
    f16x8 v = *(const f16x8*)(base + (size_t)(128 + row) * P + c8);
#pragma unroll
    for (int j = 0; j < 8; ++j) {
      int h = c8 + j;
      int kc = row ^ (((h >> 3) & 7) << 3);
      Vt[h * 72 + kc] = v[j];
    }
  }
  __syncthreads();

  f32x4 e[4] = {};
#pragma unroll
  for (int kk = 0; kk < 4; ++kk) {
#pragma unroll
    for (int nt = 0; nt < 4; ++nt) {
      f16x8 bk = *(const f16x8*)&Kl[(nt * 16 + l15) * 136 + kk * 32 + quad * 8];
      e[nt] = MFMA16(aq[kk], bk, e[nt]);
    }
  }
  // softmax: lane holds E[q = m0+quad*4+r][k = nt*16+l15]; rows span 16 lanes
  float pr[4][4];
  float rinv[4];
#pragma unroll
  for (int r = 0; r < 4; ++r) {
    float mx = fmaxf(fmaxf(e[0][r], e[1][r]), fmaxf(e[2][r], e[3][r]));
    for (int off = 1; off < 16; off <<= 1) mx = fmaxf(mx, __shfl_xor(mx, off));
    float sm = 0.f;
#pragma unroll
    for (int nt = 0; nt < 4; ++nt) {
      float pv = __expf(e[nt][r] - mx);
      pr[nt][r] = pv;
      sm += pv;
    }
    for (int off = 1; off < 16; off <<= 1) sm += __shfl_xor(sm, off);
    rinv[r] = 1.0f / sm;
  }
  __syncthreads();  // all E reads of Kl done before Al (same region) overwrite

  // P into Al (stride 72). Rows m0..m0+15 are written AND read only by this
  // wave -> no barrier needed before PV (compiler inserts lgkmcnt).
#pragma unroll
  for (int nt = 0; nt < 4; ++nt)
#pragma unroll
    for (int r = 0; r < 4; ++r)
      Al[(m0 + quad * 4 + r) * 72 + nt * 16 + l15] = (f16)(pr[nt][r] * rinv[r]);

  f32x4 o[8] = {};
#pragma unroll
  for (int kk = 0; kk < 2; ++kk) {
    f16x8 ap = *(const f16x8*)&Al[(m0 + l15) * 72 + kk * 32 + quad * 8];
#pragma unroll
    for (int nt = 0; nt < 8; ++nt) {
      int hr = nt * 16 + l15;
      int kb = (kk * 32 + quad * 8) ^ (((hr >> 3) & 7) << 3);
      f16x8 bv = *(const f16x8*)&Vt[hr * 72 + kb];
      o[nt] = MFMA16(ap, bv, o[nt]);
    }
  }
  __syncthreads();  // Vt and all waves' Al dead before Ol overwrite

  // O bounce through LDS (stride 136, XOR by (row&15)<<3 -> 2-way max) for
  // coalesced f16x8 global stores. Rows wave-private -> no barrier after.
#pragma unroll
  for (int nt = 0; nt < 8; ++nt)
#pragma unroll
    for (int r = 0; r < 4; ++r) {
      int row = m0 + quad * 4 + r;
      int col = nt * 16 + l15;
      Ol[row * 136 + (col ^ ((row & 15) << 3))] = (f16)o[nt][r];
    }
  f16* db = dst + (size_t)b * COUT * P + (size_t)s * HW;
#pragma unroll
  for (int it = 0; it < 4; ++it) {
    int c = lane + it * 64;
    int row = m0 + (c >> 4);
    int c8 = (c & 15) * 8;
    f16x8 vv = *(const f16x8*)&Ol[row * 136 + (c8 ^ ((row & 15) << 3))];
    *(f16x8*)(db + (size_t)row * P + c8) = vv;
  }
}

// ---------------------------------------------------------------------------
// Kernel 3: out projection + bias + gamma + residual.
// grid (128 2D-tiles, 8 b), block 256; m-tile loop (8x 64 rows) inside.
// Tile = 8h x 16w. S = ahT (transposed layout, read 16B chunks along h) +
// avN (natural), combined in LDS via two passes. W read pre-converted f16.
// D row->p, col->m: float4 residual load + float4 store on full 64B lines.
// ---------------------------------------------------------------------------
__global__ __launch_bounds__(256) void out_proj(
    const f16* __restrict__ ahT, const f16* __restrict__ av,
    const f16* __restrict__ w16, const float* __restrict__ bias,
    const float* __restrict__ gamma_p, const float* __restrict__ x,
    float* __restrict__ out)
{
  __shared__ __attribute__((aligned(16))) f16 St[128 * 72];
  const int bx = blockIdx.x;
  const int h0 = (bx >> 3) * 8, w0 = (bx & 7) * 16;
  const int b = blockIdx.y;
  const int t = threadIdx.x;
  const int lane = t & 63, wv = t >> 6;
  const int quad = lane >> 4, l15 = lane & 15;
  const int wm = (wv >> 1) * 32, wn = (wv & 1) * 64;

  const size_t abase = (size_t)b * COUT * P;
  // pass 1: av natural [k][h0+hh][w0+w8..+7] -> St[p][k] scatter (swizzled)
  for (int it = 0; it < 4; ++it) {
    int c = t + it * 256;
    int k = c >> 4, sub = c & 15;
    int hh = sub >> 1, w8 = (sub & 1) * 8;
    f16x8 vv = *(const f16x8*)(av + abase + (size_t)k * P + (h0 + hh) * 128 + w0 + w8);
#pragma unroll
    for (int j = 0; j < 8; ++j) {
      int p = hh * 16 + w8 + j;
      St[p * 72 + (k ^ (((p >> 3) & 7) << 3))] = vv[j];
    }
  }
  __syncthreads();
  // pass 2: ahT [k][w0+ww][h0..h0+7] -> add into St
  for (int it = 0; it < 4; ++it) {
    int c = t + it * 256;
    int k = c >> 4, ww = c & 15;
    f16x8 vv = *(const f16x8*)(ahT + abase + (size_t)k * P + (size_t)(w0 + ww) * 128 + h0);
#pragma unroll
    for (int j = 0; j < 8; ++j) {
      int p = j * 16 + ww;
      int idx = p * 72 + (k ^ (((p >> 3) & 7) << 3));
      St[idx] = St[idx] + vv[j];
    }
  }
  __syncthreads();

  // hoist S fragments into registers once (St dead afterwards)
  f16x8 sf[2][4];   // [kk][p-sub]
#pragma unroll
  for (int kk = 0; kk < 2; ++kk)
#pragma unroll
    for (int ps = 0; ps < 4; ++ps) {
      int pr2 = wn + ps * 16 + l15;
      int kb = (kk * 32 + quad * 8) ^ (((pr2 >> 3) & 7) << 3);
      sf[kk][ps] = *(const f16x8*)&St[pr2 * 72 + kb];
    }

  const float g = *gamma_p;
  const float* xb = x + (size_t)b * CIN * P;
  float* ob = out + (size_t)b * CIN * P;

  for (int mt = 0; mt < 8; ++mt) {
    const int m0 = mt * 64;
    f16x8 wf[2][2];  // [kk][m-sub]
#pragma unroll
    for (int ms = 0; ms < 2; ++ms) {
      const f16* wr = w16 + (size_t)(m0 + wm + ms * 16 + l15) * COUT;
#pragma unroll
      for (int kk = 0; kk < 2; ++kk)
        wf[kk][ms] = *(const f16x8*)(wr + kk * 32 + quad * 8);
    }
    f32x4 acc[4][2] = {};   // [p-sub][m-sub]
#pragma unroll
    for (int kk = 0; kk < 2; ++kk)
#pragma unroll
      for (int ps = 0; ps < 4; ++ps)
#pragma unroll
        for (int ms = 0; ms < 2; ++ms)
          acc[ps][ms] = MFMA16(sf[kk][ps], wf[kk][ms], acc[ps][ms]);
#pragma unroll
    for (int ms = 0; ms < 2; ++ms) {
      int m = m0 + wm + ms * 16 + l15;
      float bi = bias[m];
#pragma unroll
      for (int ps = 0; ps < 4; ++ps) {
        int pst = wn + ps * 16 + quad * 4;
        int hh = pst >> 4, ww = pst & 15;
        size_t idx = (size_t)m * P + (h0 + hh) * 128 + w0 + ww;
        const float4 xv = *(const float4*)(xb + idx);
        float4 ov;
        ov.x = g * acc[ps][ms][0] + bi + xv.x;
        ov.y = g * acc[ps][ms][1] + bi + xv.y;
        ov.z = g * acc[ps][ms][2] + bi + xv.z;
        ov.w = g * acc[ps][ms][3] + bi + xv.w;
        *(float4*)(ob + idx) = ov;
      }
    }
  }
}

// ---------------------------------------------------------------------------
extern "C" void kernel_launch(void* const* d_in, const int* in_sizes, int n_in,
                              void* d_out, int out_size, void* d_ws,
                              size_t ws_size, hipStream_t stream)
{
  (void)in_sizes; (void)n_in; (void)out_size; (void)ws_size;
  const float* x = (const float*)d_in[0];
  const float* qkv_w = (const float*)d_in[1];
  const float* qkv_b = (const float*)d_in[2];
  const float* out_w = (const float*)d_in[3];
  const float* out_b = (const float*)d_in[4];
  const float* gamma = (const float*)d_in[5];
  float* out = (float*)d_out;

  char* ws = (char*)d_ws;
  const size_t QKV_BYTES = (size_t)8 * QKV_CH * P * sizeof(f16);   // 48 MiB
  const size_t ATT_BYTES = (size_t)8 * COUT * P * sizeof(f16);     // 16 MiB
  f16* qkv  = (f16*)ws;
  f16* qkvT = (f16*)(ws + QKV_BYTES);
  f16* ahT  = (f16*)(ws + 2 * QKV_BYTES);
  f16* avN  = (f16*)(ws + 2 * QKV_BYTES + ATT_BYTES);
  f16* wq16 = (f16*)(ws + 2 * QKV_BYTES + 2 * ATT_BYTES);
  f16* wo16 = wq16 + (size_t)QKV_CH * CIN;

  prep_w<<<dim3(128), 256, 0, stream>>>(qkv_w, out_w, wq16, wo16);
  qkv_gemm<<<dim3(128, 8), 256, 0, stream>>>(x, wq16, qkv_b, qkv, qkvT);
  cc_attn<<<dim3(128, 8, 2), 256, 0, stream>>>(qkvT, qkv, ahT, avN);
  out_proj<<<dim3(128, 8), 256, 0, stream>>>(ahT, avN, wo16, out_b, gamma,
                                             x, out);
}

// Round 4
// 600.779 us; speedup vs baseline: 1.0934x; 1.0934x over previous
//
#include <hip/hip_runtime.h>

// CrissCrossAttention on MI355X (gfx950), fp16-MFMA pipeline, fp32 accumulate.
//
// Pipeline (6 launches, all on `stream`):
//   0) prep_w    : qkv_w, out_w fp32 -> f16 (once, 260 KB)
//   1) qkv_gemm  : qkv[b,192,p] = f16(qkv_w @ x + qkv_b)             (MFMA f16)
//   2) transpose : qkvT[b,o,w,h] = qkv[b,o,h,w]                      (LDS tile)
//   3) cc_attn   : z=0 horizontal (qkvT -> ahT), z=1 vertical (qkv -> avN)
//   4) transpose : ahN[b,c,h,w] = ahT[b,c,w,h]
//   5) out_proj  : out = gamma*(out_w @ (ahN+avN)) + out_b + x       (MFMA)
//
// R4 vs R3 (656 us, regressed from R2's 601): REVERTED the transpose fusion
// (Cl bounce cost 1.46e7 LDS bank conflicts + partial-line transposed stores).
// Kept from R3: f16 weight pre-conversion, K-loop register prefetch.
// New: out_proj p-tile 128->64 (LDS 18->9 KB), grid (256,8), lb(256,5)
// to fix the measured 22% occupancy on a pure-streaming kernel.
//
// Workspace: qkv 48 | qkvT 48 | ahT 16 | ahN 16 | avN 16 MB | wq16 | wo16

typedef _Float16 f16;
typedef _Float16 f16x4 __attribute__((ext_vector_type(4)));
typedef _Float16 f16x8 __attribute__((ext_vector_type(8)));
typedef float f32x4 __attribute__((ext_vector_type(4)));

#define MFMA16(a, b, c) __builtin_amdgcn_mfma_f32_16x16x32_f16(a, b, c, 0, 0, 0)

constexpr int CIN = 512;
constexpr int COUT = 64;       // per q/k/v
constexpr int HW = 128;
constexpr int P = HW * HW;     // 16384 pixels per batch
constexpr int QKV_CH = 192;

// ---------------------------------------------------------------------------
// Kernel 0: one-shot weight conversion fp32 -> f16.
// qkv_w 192x512 (24576 float4) + out_w 512x64 (8192 float4) = 32768 float4.
// ---------------------------------------------------------------------------
__global__ __launch_bounds__(256) void prep_w(
    const float* __restrict__ qw, const float* __restrict__ ow,
    f16* __restrict__ qw16, f16* __restrict__ ow16)
{
  int i = blockIdx.x * 256 + threadIdx.x;    // 0..32767
  const float* src;
  f16* dst;
  int off;
  if (i < 24576) { src = qw; dst = qw16; off = i; }
  else           { src = ow; dst = ow16; off = i - 24576; }
  const float4 v = *(const float4*)(src + (size_t)off * 4);
  f16x4 o;
  o[0] = (f16)v.x; o[1] = (f16)v.y; o[2] = (f16)v.z; o[3] = (f16)v.w;
  *(f16x4*)(dst + (size_t)off * 4) = o;
}

// ---------------------------------------------------------------------------
// Kernel 1: QKV projection GEMM.  C[192m x 128n] per block, K=512 in 32-chunks.
// grid (128 ntiles, 8 b), block 256 (4 waves, 2x2 wave grid), m-loop inside.
// Register prefetch of step s+1's W/X overlaps global latency with MFMA.
// MFMA: A = X frag (p rows), B = W frag (m rows); D row->p, col->m.
// ---------------------------------------------------------------------------
__global__ __launch_bounds__(256) void qkv_gemm(
    const float* __restrict__ x, const f16* __restrict__ w16,
    const float* __restrict__ bias, f16* __restrict__ qkv)
{
  // Wl: [192 m][32 k] stride 40; Xt: [128 p][32 k] stride 40, XOR-swizzled.
  __shared__ __attribute__((aligned(16))) f16 Wl[QKV_CH * 40];
  __shared__ __attribute__((aligned(16))) f16 Xt[128 * 40];
  const int p0 = blockIdx.x * 128;
  const int b = blockIdx.y;
  const float* xb = x + (size_t)b * CIN * P;
  const int t = threadIdx.x;
  const int lane = t & 63, wv = t >> 6;
  const int quad = lane >> 4, l15 = lane & 15;
  const int wm = (wv >> 1) * 32, wn = (wv & 1) * 64;

  f16x8 wvr[3];
  float4 xvr[4];
#define LOADW(s)                                                          \
  _Pragma("unroll") for (int it = 0; it < 3; ++it) {                      \
    int c = t + it * 256;                                                 \
    wvr[it] = *(const f16x8*)(w16 + (size_t)(c >> 2) * CIN + (s) * 32 +   \
                              (c & 3) * 8);                               \
  }
#define LOADX(s)                                                          \
  _Pragma("unroll") for (int it = 0; it < 4; ++it) {                      \
    int c = t + it * 256;                                                 \
    xvr[it] = *(const float4*)(xb + (size_t)((s) * 32 + (c >> 5)) * P +   \
                               p0 + (c & 31) * 4);                        \
  }

  LOADW(0);
  LOADX(0);
  f32x4 acc[3][4][2] = {};   // [m-tile][p-sub][m-sub]
  for (int s = 0; s < 16; ++s) {
    // write staged regs to LDS
#pragma unroll
    for (int it = 0; it < 3; ++it) {
      int c = t + it * 256;
      *(f16x8*)&Wl[(c >> 2) * 40 + (c & 3) * 8] = wvr[it];
    }
#pragma unroll
    for (int it = 0; it < 4; ++it) {
      int c = t + it * 256;
      int kr = c >> 5, p4 = (c & 31) * 4;
      float vv[4] = {xvr[it].x, xvr[it].y, xvr[it].z, xvr[it].w};
#pragma unroll
      for (int j = 0; j < 4; ++j) {
        int p = p4 + j;
        int kc = kr ^ (((p >> 3) & 3) << 3);
        Xt[p * 40 + kc] = (f16)vv[j];
      }
    }
    __syncthreads();
    if (s < 15) { LOADW(s + 1); LOADX(s + 1); }   // overlap with MFMA below
    f16x8 xf[4];
#pragma unroll
    for (int ps = 0; ps < 4; ++ps) {
      int pr = wn + ps * 16 + l15;
      int kb = (quad * 8) ^ (((pr >> 3) & 3) << 3);
      xf[ps] = *(const f16x8*)&Xt[pr * 40 + kb];
    }
#pragma unroll
    for (int mt = 0; mt < 3; ++mt) {
      f16x8 wf[2];
#pragma unroll
      for (int ms = 0; ms < 2; ++ms)
        wf[ms] = *(const f16x8*)&Wl[(mt * 64 + wm + ms * 16 + l15) * 40 + quad * 8];
#pragma unroll
      for (int ps = 0; ps < 4; ++ps)
#pragma unroll
        for (int ms = 0; ms < 2; ++ms)
          acc[mt][ps][ms] = MFMA16(xf[ps], wf[ms], acc[mt][ps][ms]);
    }
    __syncthreads();
  }
#undef LOADW
#undef LOADX

  f16* ob = qkv + (size_t)b * QKV_CH * P;
#pragma unroll
  for (int mt = 0; mt < 3; ++mt) {
#pragma unroll
    for (int ms = 0; ms < 2; ++ms) {
      int m = mt * 64 + wm + ms * 16 + l15;
      float bi = bias[m];
#pragma unroll
      for (int ps = 0; ps < 4; ++ps) {
        int p = p0 + wn + ps * 16 + quad * 4;
        f16x4 tmp;
#pragma unroll
        for (int r = 0; r < 4; ++r) tmp[r] = (f16)(acc[mt][ps][ms][r] + bi);
        *(f16x4*)(ob + (size_t)m * P + p) = tmp;
      }
    }
  }
}

// ---------------------------------------------------------------------------
// Kernel 2/4: spatial 128x128 transpose per channel plane, 64x64 tiles.
// grid (planes, 2, 2), block 256.
// ---------------------------------------------------------------------------
__global__ __launch_bounds__(256) void transpose_hw(
    const f16* __restrict__ in, f16* __restrict__ out)
{
  __shared__ __attribute__((aligned(16))) f16 T[64 * 72];
  const size_t plane = blockIdx.x;
  const int r0 = blockIdx.y * 64, c0 = blockIdx.z * 64;
  const f16* ip = in + plane * P;
  f16* op = out + plane * P;
  const int t = threadIdx.x;
  for (int it = 0; it < 2; ++it) {
    int c = t + it * 256;              // 512 chunks of 8
    int row = c >> 3, c8 = (c & 7) * 8;
    *(f16x8*)&T[row * 72 + c8] =
        *(const f16x8*)(ip + (size_t)(r0 + row) * HW + c0 + c8);
  }
  __syncthreads();
  for (int it = 0; it < 2; ++it) {
    int c = t + it * 256;
    int wr = c >> 3, h8 = (c & 7) * 8;
    f16 tmp[8];
#pragma unroll
    for (int j = 0; j < 8; ++j) tmp[j] = T[(h8 + j) * 72 + wr];
    *(f16x8*)(op + (size_t)(c0 + wr) * HW + r0 + h8) = *(const f16x8*)tmp;
  }
}

// ---------------------------------------------------------------------------
// Kernel 3: criss-cross attention over one line (row or column).
// grid (128 s, 8 b, 2 branch), block 256 (4 waves, each owns a 16-q strip).
// Input slice layout (both branches): elem(o, j) = src[b*192*P + o*P + s*128 + j]
// E[64q x 64k] = sum_j Q[q,j] K[k,j]  -> softmax over k -> O = P V [64q x 128j]
// LDS: Kl 64x136 (K; reused as Al stride 72 after E, then Ol stride 136 after
// PV), Vt 128x72 swizzled.  Total 35.8 KB -> 4 blocks/CU.
// ---------------------------------------------------------------------------
__global__ __launch_bounds__(256, 4) void cc_attn(
    const f16* __restrict__ qkvT, const f16* __restrict__ qkvN,
    f16* __restrict__ outT, f16* __restrict__ outN)
{
  __shared__ __attribute__((aligned(16))) f16 smem[64 * 136 + 128 * 72];
  f16* Kl = smem;
  f16* Vt = smem + 64 * 136;
  f16* Al = smem;  // reuse of Kl region after E (wave-private rows)
  f16* Ol = smem;  // reuse of Kl region after PV (wave-private rows)
  const int s = blockIdx.x, b = blockIdx.y;
  const f16* src = blockIdx.z ? qkvN : qkvT;
  f16* dst = blockIdx.z ? outN : outT;
  const f16* base = src + (size_t)b * QKV_CH * P + (size_t)s * HW;
  const int t = threadIdx.x;
  const int lane = t & 63, wv = t >> 6;
  const int quad = lane >> 4, l15 = lane & 15;
  const int m0 = wv * 16;  // this wave's q-strip

  // Q fragments straight from global into regs (wave-private rows m0..m0+15).
  f16x8 aq[4];
#pragma unroll
  for (int kk = 0; kk < 4; ++kk)
    aq[kk] = *(const f16x8*)(base + (size_t)(m0 + l15) * P + kk * 32 + quad * 8);

  // stage K (natural) and V (transposed+swizzled): 1024 chunks of 8 each
  for (int it = 0; it < 4; ++it) {
    int c = t + it * 256;
    int row = c >> 4, c8 = (c & 15) * 8;
    *(f16x8*)&Kl[row * 136 + c8] =
        *(const f16x8*)(base + (size_t)(64 + row) * P + c8);
    f16x8 v = *(const f16x8*)(base + (size_t)(128 + row) * P + c8);
#pragma unroll
    for (int j = 0; j < 8; ++j) {
      int h = c8 + j;
      int kc = row ^ (((h >> 3) & 7) << 3);
      Vt[h * 72 + kc] = v[j];
    }
  }
  __syncthreads();

  f32x4 e[4] = {};
#pragma unroll
  for (int kk = 0; kk < 4; ++kk) {
#pragma unroll
    for (int nt = 0; nt < 4; ++nt) {
      f16x8 bk = *(const f16x8*)&Kl[(nt * 16 + l15) * 136 + kk * 32 + quad * 8];
      e[nt] = MFMA16(aq[kk], bk, e[nt]);
    }
  }
  // softmax: lane holds E[q = m0+quad*4+r][k = nt*16+l15]; rows span 16 lanes
  float pr[4][4];
  float rinv[4];
#pragma unroll
  for (int r = 0; r < 4; ++r) {
    float mx = fmaxf(fmaxf(e[0][r], e[1][r]), fmaxf(e[2][r], e[3][r]));
    for (int off = 1; off < 16; off <<= 1) mx = fmaxf(mx, __shfl_xor(mx, off));
    float sm = 0.f;
#pragma unroll
    for (int nt = 0; nt < 4; ++nt) {
      float pv = __expf(e[nt][r] - mx);
      pr[nt][r] = pv;
      sm += pv;
    }
    for (int off = 1; off < 16; off <<= 1) sm += __shfl_xor(sm, off);
    rinv[r] = 1.0f / sm;
  }
  __syncthreads();  // all E reads of Kl done before Al (same region) overwrite

  // P into Al (stride 72). Rows m0..m0+15 are written AND read only by this
  // wave -> no barrier needed before PV (compiler inserts lgkmcnt).
#pragma unroll
  for (int nt = 0; nt < 4; ++nt)
#pragma unroll
    for (int r = 0; r < 4; ++r)
      Al[(m0 + quad * 4 + r) * 72 + nt * 16 + l15] = (f16)(pr[nt][r] * rinv[r]);

  f32x4 o[8] = {};
#pragma unroll
  for (int kk = 0; kk < 2; ++kk) {
    f16x8 ap = *(const f16x8*)&Al[(m0 + l15) * 72 + kk * 32 + quad * 8];
#pragma unroll
    for (int nt = 0; nt < 8; ++nt) {
      int hr = nt * 16 + l15;
      int kb = (kk * 32 + quad * 8) ^ (((hr >> 3) & 7) << 3);
      f16x8 bv = *(const f16x8*)&Vt[hr * 72 + kb];
      o[nt] = MFMA16(ap, bv, o[nt]);
    }
  }
  __syncthreads();  // Vt and all waves' Al dead before Ol overwrite

  // O bounce through LDS (stride 136, XOR by (row&15)<<3 -> 2-way max) for
  // coalesced f16x8 global stores. Rows wave-private -> no barrier after.
#pragma unroll
  for (int nt = 0; nt < 8; ++nt)
#pragma unroll
    for (int r = 0; r < 4; ++r) {
      int row = m0 + quad * 4 + r;
      int col = nt * 16 + l15;
      Ol[row * 136 + (col ^ ((row & 15) << 3))] = (f16)o[nt][r];
    }
  f16* db = dst + (size_t)b * COUT * P + (size_t)s * HW;
#pragma unroll
  for (int it = 0; it < 4; ++it) {
    int c = lane + it * 64;
    int row = m0 + (c >> 4);
    int c8 = (c & 15) * 8;
    f16x8 vv = *(const f16x8*)&Ol[row * 136 + (c8 ^ ((row & 15) << 3))];
    *(f16x8*)(db + (size_t)row * P + c8) = vv;
  }
}

// ---------------------------------------------------------------------------
// Kernel 5: out projection + bias + gamma + residual.
// grid (256 ptiles, 8 b), block 256; p-tile = 64, m-tile loop (8x 64) inside.
// LDS 9 KB + lb(256,5) -> ~20 waves/CU (fixes measured 22% occupancy).
// S fragments hoisted to regs once; W read pre-converted f16 (L2-hot).
// D row->p, col->m: float4 residual load + float4 store on 64B granules.
// ---------------------------------------------------------------------------
__global__ __launch_bounds__(256, 5) void out_proj(
    const f16* __restrict__ ah, const f16* __restrict__ av,
    const f16* __restrict__ w16, const float* __restrict__ bias,
    const float* __restrict__ gamma_p, const float* __restrict__ x,
    float* __restrict__ out)
{
  __shared__ __attribute__((aligned(16))) f16 St[64 * 72];
  const int p0 = blockIdx.x * 64;
  const int b = blockIdx.y;
  const int t = threadIdx.x;
  const int lane = t & 63, wv = t >> 6;
  const int quad = lane >> 4, l15 = lane & 15;

  // stage S = attn_h + attn_v, transposed into St[p][k] with column swizzle
  const size_t abase = (size_t)b * COUT * P + p0;
  for (int it = 0; it < 2; ++it) {
    int c = t + it * 256;              // 512 chunks of 8
    int k = c >> 3, p8 = (c & 7) * 8;
    f16x8 a = *(const f16x8*)(ah + abase + (size_t)k * P + p8);
    f16x8 vv = *(const f16x8*)(av + abase + (size_t)k * P + p8);
#pragma unroll
    for (int j = 0; j < 8; ++j) {
      int p = p8 + j;
      St[p * 72 + (k ^ (((p >> 3) & 7) << 3))] = (f16)(a[j] + vv[j]);
    }
  }
  __syncthreads();

  // hoist S fragments into registers once (St dead afterwards)
  f16x8 sf[2][4];   // [kk][p-sub]
#pragma unroll
  for (int kk = 0; kk < 2; ++kk)
#pragma unroll
    for (int ps = 0; ps < 4; ++ps) {
      int pr2 = ps * 16 + l15;
      int kb = (kk * 32 + quad * 8) ^ (((pr2 >> 3) & 7) << 3);
      sf[kk][ps] = *(const f16x8*)&St[pr2 * 72 + kb];
    }

  const float g = *gamma_p;
  const float* xb = x + (size_t)b * CIN * P;
  float* ob = out + (size_t)b * CIN * P;

  for (int mt = 0; mt < 8; ++mt) {
    const int m = mt * 64 + wv * 16 + l15;   // this lane's output channel
    f16x8 wf[2];
#pragma unroll
    for (int kk = 0; kk < 2; ++kk)
      wf[kk] = *(const f16x8*)(w16 + (size_t)m * COUT + kk * 32 + quad * 8);
    f32x4 acc[4] = {};   // [p-sub]
#pragma unroll
    for (int kk = 0; kk < 2; ++kk)
#pragma unroll
      for (int ps = 0; ps < 4; ++ps)
        acc[ps] = MFMA16(sf[kk][ps], wf[kk], acc[ps]);
    float bi = bias[m];
#pragma unroll
    for (int ps = 0; ps < 4; ++ps) {
      int p = p0 + ps * 16 + quad * 4;
      size_t idx = (size_t)m * P + p;
      const float4 xv = *(const float4*)(xb + idx);
      float4 ov;
      ov.x = g * acc[ps][0] + bi + xv.x;
      ov.y = g * acc[ps][1] + bi + xv.y;
      ov.z = g * acc[ps][2] + bi + xv.z;
      ov.w = g * acc[ps][3] + bi + xv.w;
      *(float4*)(ob + idx) = ov;
    }
  }
}

// ---------------------------------------------------------------------------
extern "C" void kernel_launch(void* const* d_in, const int* in_sizes, int n_in,
                              void* d_out, int out_size, void* d_ws,
                              size_t ws_size, hipStream_t stream)
{
  (void)in_sizes; (void)n_in; (void)out_size; (void)ws_size;
  const float* x = (const float*)d_in[0];
  const float* qkv_w = (const float*)d_in[1];
  const float* qkv_b = (const float*)d_in[2];
  const float* out_w = (const float*)d_in[3];
  const float* out_b = (const float*)d_in[4];
  const float* gamma = (const float*)d_in[5];
  float* out = (float*)d_out;

  char* ws = (char*)d_ws;
  const size_t QKV_BYTES = (size_t)8 * QKV_CH * P * sizeof(f16);   // 48 MiB
  const size_t ATT_BYTES = (size_t)8 * COUT * P * sizeof(f16);     // 16 MiB
  f16* qkv  = (f16*)ws;
  f16* qkvT = (f16*)(ws + QKV_BYTES);
  f16* ahT  = (f16*)(ws + 2 * QKV_BYTES);
  f16* ahN  = (f16*)(ws + 2 * QKV_BYTES + ATT_BYTES);
  f16* avN  = (f16*)(ws + 2 * QKV_BYTES + 2 * ATT_BYTES);
  f16* wq16 = (f16*)(ws + 2 * QKV_BYTES + 3 * ATT_BYTES);
  f16* wo16 = wq16 + (size_t)QKV_CH * CIN;

  prep_w<<<dim3(128), 256, 0, stream>>>(qkv_w, out_w, wq16, wo16);
  qkv_gemm<<<dim3(128, 8), 256, 0, stream>>>(x, wq16, qkv_b, qkv);
  transpose_hw<<<dim3(8 * QKV_CH, 2, 2), 256, 0, stream>>>(qkv, qkvT);
  cc_attn<<<dim3(128, 8, 2), 256, 0, stream>>>(qkvT, qkv, ahT, avN);
  transpose_hw<<<dim3(8 * COUT, 2, 2), 256, 0, stream>>>(ahT, ahN);
  out_proj<<<dim3(256, 8), 256, 0, stream>>>(ahN, avN, wo16, out_b, gamma,
                                             x, out);
}